// Round 1
// 346.433 us; speedup vs baseline: 1.0242x; 1.0242x over previous
//
#include <hip/hip_runtime.h>
#include <hip/hip_bf16.h>
#include <math.h>

// x(32,512,768) fp32 -> LayerNorm(768) -> Linear 768x3072 + bias -> exact GELU
// M = 16384, K = 768, N = 3072. Output fp32.
#define M_ROWS 16384
#define K_DIM  768
#define N_DIM  3072
#define NT     12      // K_DIM / 64 K-tiles

typedef __bf16 bf16x8 __attribute__((ext_vector_type(8)));
typedef float  f32x4  __attribute__((ext_vector_type(4)));
typedef unsigned short u16x4 __attribute__((ext_vector_type(4)));

__device__ __forceinline__ unsigned short f2bf(float f) {
    unsigned int u = __float_as_uint(f);
    unsigned int r = (u + 0x7fffu + ((u >> 16) & 1u)) >> 16;   // RNE
    return (unsigned short)r;
}

__device__ __forceinline__ void async16(const unsigned short* g, unsigned short* l) {
    __builtin_amdgcn_global_load_lds(
        (const __attribute__((address_space(1))) unsigned int*)g,
        (__attribute__((address_space(3))) unsigned int*)l,
        16, 0, 0);
}

// tanh-form GELU: 0.5h(1+tanh(0.79788456(h+0.044715h^3))); max |err| vs erf ~1e-3
__device__ __forceinline__ float gelu_fast(float h) {
    float h2 = h * h;
    float z2 = h * __builtin_fmaf(0.0713548162f, h2, 1.5957691216f); // 2*z
    float E  = __expf(z2);                                           // e^{2z}
    float r  = __builtin_amdgcn_rcpf(1.0f + E);                      // (1-tanh)/2
    return h - h * r;                                                // 0.5h(1+tanh)
}

// ---------- 1) LayerNorm + cast to bf16 (vectorized) ----------
__global__ __launch_bounds__(256) void ln_kernel(const float* __restrict__ x,
                                                 const float* __restrict__ gamma,
                                                 const float* __restrict__ beta,
                                                 unsigned short* __restrict__ xn) {
    int wave = threadIdx.x >> 6;
    int lane = threadIdx.x & 63;
    int row  = blockIdx.x * 4 + wave;
    const f32x4* xr = (const f32x4*)(x + (size_t)row * K_DIM);
    const f32x4* g4 = (const f32x4*)gamma;
    const f32x4* b4 = (const f32x4*)beta;

    f32x4 v[3];
    float s = 0.f, ss = 0.f;
#pragma unroll
    for (int q = 0; q < 3; q++) {
        v[q] = xr[lane + 64 * q];
#pragma unroll
        for (int e = 0; e < 4; e++) { s += v[q][e]; ss += v[q][e] * v[q][e]; }
    }
#pragma unroll
    for (int off = 32; off; off >>= 1) {
        s  += __shfl_xor(s,  off, 64);
        ss += __shfl_xor(ss, off, 64);
    }
    float mu   = s * (1.f / K_DIM);
    float var  = ss * (1.f / K_DIM) - mu * mu;
    float rstd = rsqrtf(var + 1e-12f);

    u16x4* xo = (u16x4*)(xn + (size_t)row * K_DIM);
#pragma unroll
    for (int q = 0; q < 3; q++) {
        f32x4 gv = g4[lane + 64 * q];
        f32x4 bv = b4[lane + 64 * q];
        u16x4 o;
#pragma unroll
        for (int e = 0; e < 4; e++)
            o[e] = f2bf((v[q][e] - mu) * rstd * gv[e] + bv[e]);
        xo[lane + 64 * q] = o;
    }
}

// ---------- 2) W [K,N] fp32 -> Wt [N,K] bf16 ----------
__global__ __launch_bounds__(256) void wcast_kernel(const float* __restrict__ W,
                                                    unsigned short* __restrict__ wt) {
    __shared__ float tile[32][33];
    int bx = blockIdx.x, by = blockIdx.y;
    int tx = threadIdx.x, ty = threadIdx.y;
#pragma unroll
    for (int r = 0; r < 4; r++)
        tile[ty + 8 * r][tx] = W[(size_t)(by * 32 + ty + 8 * r) * N_DIM + bx * 32 + tx];
    __syncthreads();
#pragma unroll
    for (int r = 0; r < 4; r++)
        wt[(size_t)(bx * 32 + ty + 8 * r) * K_DIM + by * 32 + tx] = f2bf(tile[tx][ty + 8 * r]);
}

// ---------- 3) GEMM + bias + GELU: 256x256 tile, BK=64, 8 waves, 8-phase ----------
// Schedule (T1+T2+T3+T4+T5 per the CDNA4 catalog):
//   - 8 waves (2M x 4N), each owns a 128x64 output; 4 phases per K-tile,
//     16 MFMA (16x16x32 bf16) per phase, snake quadrant order
//     P1:(j0-3,i0-1) P2:(j0-3,i2-3) P3:(j4-7,i2-3) P4:(j4-7,i0-1)
//     so A-unit0 is dead after P1, B-unit1 after P3, etc.
//   - staging units of 16KB (2 global_load_lds/thread), 1 unit per phase:
//     P1: UA1(t+1)  P2: UB0(t+1)  -> other buffer (safe: freed last tile)
//     P3: UA0(t+2)  P4: UB1(t+2)  -> CURRENT buffer, but only regions whose
//     reads completed before an earlier barrier this tile (race-checked).
//   - counted s_waitcnt vmcnt(4) once per K-tile boundary (vmcnt(0) only
//     before the last tile); raw s_barrier (no full drain) x2 per phase.
//   - LDS chunk-XOR swizzle chunk' = chunk ^ (row&7): pre-swizzled global
//     source + linear LDS dest (global_load_lds constraint), swizzled read.
//   - s_setprio(1) around each MFMA cluster; bijective XCD block swizzle.
__global__ __launch_bounds__(512, 2) void gemm_kernel(const unsigned short* __restrict__ A,
                                                      const unsigned short* __restrict__ B,
                                                      const float* __restrict__ bias,
                                                      float* __restrict__ C) {
    __shared__ __attribute__((aligned(16))) unsigned short As[2][256 * 64];
    __shared__ __attribute__((aligned(16))) unsigned short Bs[2][256 * 64];

    int tid   = threadIdx.x;
    int lane  = tid & 63;
    int wid   = tid >> 6;
    int waveM = wid >> 2;        // 0..1 -> 128 M-rows each
    int waveN = wid & 3;         // 0..3 -> 64 N-cols each

    // XCD-aware bijective swizzle: 768 blocks, 768 % 8 == 0
    int orig = blockIdx.y * 12 + blockIdx.x;
    int wg   = (orig & 7) * 96 + (orig >> 3);
    int bm   = wg / 12;
    int bn   = wg - bm * 12;

    const unsigned short* Ag = A + (size_t)bm * 256 * K_DIM;
    const unsigned short* Bg = B + (size_t)bn * 256 * K_DIM;

    // staging geometry: per unit, thread covers (row_in_unit = l*64 + rsub, chunk = cch)
    int rsub = wid * 8 + (lane >> 3);   // 0..63, wave-contiguous 8-row span
    int cch  = lane & 7;
    int sch  = cch ^ (rsub & 7);        // pre-swizzled source chunk (row&7 == rsub&7)

    int mrow = lane & 15;
    int quad = lane >> 4;
    int swz  = mrow & 7;

    f32x4 acc[4][8] = {};   // acc[i][j]: i -> N (wave 64), j -> M (wave 128)

    // A unit a: rows {a*64..a*64+63} U {128+a*64..191+a*64}
#define STAGE_A(a, kt, bfi) do { \
        _Pragma("unroll") \
        for (int l = 0; l < 2; ++l) { \
            int pr = l * 128 + (a) * 64 + rsub; \
            async16(Ag + (size_t)pr * K_DIM + (kt) * 64 + sch * 8, \
                    &As[bfi][pr * 64 + cch * 8]); \
        } } while (0)
    // B unit b: rows {b*32+[0,32)} U {64+b*32+[0,32)} U (+128 for l=1)
#define STAGE_B(b, kt, bfi) do { \
        _Pragma("unroll") \
        for (int l = 0; l < 2; ++l) { \
            int pr = l * 128 + (b) * 32 + (rsub & 31) + ((rsub >> 5) << 6); \
            async16(Bg + (size_t)pr * K_DIM + (kt) * 64 + sch * 8, \
                    &Bs[bfi][pr * 64 + cch * 8]); \
        } } while (0)

#define RD_X(j, kk, bfi) (*(const bf16x8*)&As[bfi][(waveM * 128 + (j) * 16 + mrow) * 64 + ((((kk) * 4 + quad) ^ swz) * 8)])
#define RD_W(i, kk, bfi) (*(const bf16x8*)&Bs[bfi][(waveN * 64  + (i) * 16 + mrow) * 64 + ((((kk) * 4 + quad) ^ swz) * 8)])

    // prologue: tile0 fully + first two units of tile1; wait leaves 2 units in flight
    STAGE_A(0, 0, 0); STAGE_B(1, 0, 0); STAGE_A(1, 0, 0); STAGE_B(0, 0, 0);
    STAGE_A(0, 1, 1); STAGE_B(1, 1, 1);
    asm volatile("s_waitcnt vmcnt(4)" ::: "memory");
    __builtin_amdgcn_s_barrier();
    asm volatile("" ::: "memory");

    bf16x8 xf[4][2], wf[2][2];

#define MFMA_QUAD(I0, J0) do { \
        asm volatile("s_waitcnt lgkmcnt(0)" ::: "memory"); \
        __builtin_amdgcn_s_setprio(1); \
        _Pragma("unroll") \
        for (int jj = 0; jj < 4; ++jj) { \
            _Pragma("unroll") \
            for (int kk = 0; kk < 2; ++kk) { \
                acc[(I0)][(J0) + jj]     = __builtin_amdgcn_mfma_f32_16x16x32_bf16(wf[0][kk], xf[jj][kk], acc[(I0)][(J0) + jj], 0, 0, 0); \
                acc[(I0) + 1][(J0) + jj] = __builtin_amdgcn_mfma_f32_16x16x32_bf16(wf[1][kk], xf[jj][kk], acc[(I0) + 1][(J0) + jj], 0, 0, 0); \
            } \
        } \
        __builtin_amdgcn_s_setprio(0); \
        asm volatile("" ::: "memory"); \
        __builtin_amdgcn_s_barrier(); \
        asm volatile("" ::: "memory"); \
    } while (0)

    for (int t = 0; t < NT; ++t) {
        int bf = t & 1, nb = bf ^ 1;

        // ---- P1: read x j0-3 (8) + w i0-1 (4); stage UA1(t+1) -> other buf
#pragma unroll
        for (int j = 0; j < 4; ++j) { xf[j][0] = RD_X(j, 0, bf); xf[j][1] = RD_X(j, 1, bf); }
        wf[0][0] = RD_W(0, 0, bf); wf[0][1] = RD_W(0, 1, bf);
        wf[1][0] = RD_W(1, 0, bf); wf[1][1] = RD_W(1, 1, bf);
        if (t + 1 < NT) STAGE_A(1, t + 1, nb);
        asm volatile("" ::: "memory");
        __builtin_amdgcn_s_barrier();
        MFMA_QUAD(0, 0);

        // ---- P2: read w i2-3 (4); stage UB0(t+1) -> other buf
        wf[0][0] = RD_W(2, 0, bf); wf[0][1] = RD_W(2, 1, bf);
        wf[1][0] = RD_W(3, 0, bf); wf[1][1] = RD_W(3, 1, bf);
        if (t + 1 < NT) STAGE_B(0, t + 1, nb);
        asm volatile("" ::: "memory");
        __builtin_amdgcn_s_barrier();
        MFMA_QUAD(2, 0);

        // ---- P3: read x j4-7 (8); stage UA0(t+2) -> CURRENT buf (UA0 freed after P1)
#pragma unroll
        for (int j = 0; j < 4; ++j) { xf[j][0] = RD_X(j + 4, 0, bf); xf[j][1] = RD_X(j + 4, 1, bf); }
        if (t + 2 < NT) STAGE_A(0, t + 2, bf);
        asm volatile("" ::: "memory");
        __builtin_amdgcn_s_barrier();
        MFMA_QUAD(2, 4);

        // ---- P4: re-read w i0-1 (4); stage UB1(t+2) -> CURRENT buf (freed after P3);
        //      K-tile boundary wait: counted vmcnt(4) (2 units stay in flight)
        wf[0][0] = RD_W(0, 0, bf); wf[0][1] = RD_W(0, 1, bf);
        wf[1][0] = RD_W(1, 0, bf); wf[1][1] = RD_W(1, 1, bf);
        if (t + 2 < NT) STAGE_B(1, t + 2, bf);
        if (t < NT - 2)       asm volatile("s_waitcnt vmcnt(4)" ::: "memory");
        else if (t == NT - 2) asm volatile("s_waitcnt vmcnt(0)" ::: "memory");
        asm volatile("" ::: "memory");
        __builtin_amdgcn_s_barrier();
        MFMA_QUAD(0, 4);
    }

    // epilogue: bias + GELU + store.
    // D layout: lane&15 -> B-operand row (m), quad*4+reg -> A-operand row (n)
    int m0 = bm * 256 + waveM * 128 + mrow;
    int n0 = bn * 256 + waveN * 64 + quad * 4;
#pragma unroll
    for (int i = 0; i < 4; ++i) {
        f32x4 bb = *(const f32x4*)(bias + n0 + i * 16);
#pragma unroll
        for (int j = 0; j < 8; ++j) {
            f32x4 o;
#pragma unroll
            for (int r = 0; r < 4; ++r)
                o[r] = gelu_fast(acc[i][j][r] + bb[r]);
            *(f32x4*)(C + (size_t)(m0 + j * 16) * N_DIM + n0 + i * 16) = o;
        }
    }
}

extern "C" void kernel_launch(void* const* d_in, const int* in_sizes, int n_in,
                              void* d_out, int out_size, void* d_ws, size_t ws_size,
                              hipStream_t stream) {
    const float* x     = (const float*)d_in[0];
    const float* gamma = (const float*)d_in[1];
    const float* beta  = (const float*)d_in[2];
    const float* W     = (const float*)d_in[3];
    const float* bias  = (const float*)d_in[4];
    float* out = (float*)d_out;

    unsigned short* xn = (unsigned short*)d_ws;
    unsigned short* wt = xn + (size_t)M_ROWS * K_DIM;

    ln_kernel<<<M_ROWS / 4, 256, 0, stream>>>(x, gamma, beta, xn);
    wcast_kernel<<<dim3(N_DIM / 32, K_DIM / 32), dim3(32, 8), 0, stream>>>(W, wt);
    gemm_kernel<<<dim3(N_DIM / 256, M_ROWS / 256), 512, 0, stream>>>(xn, wt, bias, out);
}